// Round 15
// baseline (751.327 us; speedup 1.0000x reference)
//
#include <hip/hip_runtime.h>
#include <cmath>

#define EPS 1e-5f
#define SLOPE 0.2f

typedef unsigned short u16;
typedef unsigned int u32;
typedef __attribute__((ext_vector_type(8))) short bf16x8;
typedef __attribute__((ext_vector_type(8))) unsigned short u16x8;
typedef __attribute__((ext_vector_type(4))) unsigned short u16x4;
typedef __attribute__((ext_vector_type(4))) float f32x4;

__device__ __forceinline__ u16 f2b(float f) {
    union { float f; u32 u; } v; v.f = f;
    u32 r = (v.u + 0x7FFF + ((v.u >> 16) & 1)) >> 16;
    return (u16)r;
}
__device__ __forceinline__ float b2f(u16 h) {
    union { u32 u; float f; } v; v.u = ((u32)h) << 16;
    return v.f;
}
__device__ __forceinline__ float leaky(float v) { return v >= 0.f ? v : SLOPE * v; }

// ---------------- fused prep: weight->bf16 converts + x padding + counter reset ----------------
__global__ __launch_bounds__(256) void prep(const float* __restrict__ x,
                                            const float* __restrict__ w0,
                                            const float* __restrict__ w1,
                                            const float* __restrict__ w2,
                                            const float* __restrict__ w3,
                                            const float* __restrict__ w4,
                                            const float* __restrict__ w5,
                                            const float* __restrict__ lw,
                                            u16* __restrict__ wbf,
                                            u16* __restrict__ w5b,
                                            u16* __restrict__ lwb,
                                            u16* __restrict__ P,
                                            u32* __restrict__ cnt) {
    int idx = blockIdx.x * 256 + threadIdx.x;
    if (idx < 8) cnt[idx] = 0;
    if (idx < 697344) {
        const float* src; int K, Kp; int base;
        if (idx < 1024)        { src = w0; K = 48;   Kp = 64;   base = 0; }
        else if (idx < 9216)   { src = w1; K = 256;  Kp = 256;  base = 1024; }
        else if (idx < 41984)  { src = w2; K = 512;  Kp = 512;  base = 9216; }
        else if (idx < 173056) { src = w3; K = 1024; Kp = 1024; base = 41984; }
        else                   { src = w4; K = 2048; Kp = 2048; base = 173056; }
        int local = idx - base;
        int k = local % Kp;
        int co = local / Kp;
        wbf[idx] = (k < K) ? f2b(src[(size_t)co * K + k]) : (u16)0;
    } else if (idx < 1745920) {
        int local = idx - 697344;
        int k = local & 1023;
        int co = local >> 10;
        w5b[local] = (co < 1000) ? f2b(w5[(size_t)co * 1024 + k]) : (u16)0;
    } else if (idx < 1811456) {
        int local = idx - 1745920;
        int k = local & 1023;
        int o = local >> 10;
        lwb[local] = (k < 1000) ? f2b(lw[(size_t)o * 1000 + k]) : (u16)0;
    } else if (idx < 3450368) {
        constexpr int H = 64, W = 768, G = 97, Wp = 776, Hp = 66;
        int local = idx - 1811456;
        int m = local % G;
        int hp = (local / G) % Hp;
        int c = (local / (G * Hp)) % 4;
        int b = local / (G * Hp * 4);
        u16x8 o;
#pragma unroll
        for (int i = 0; i < 8; ++i) o[i] = 0;
        if (c < 3 && hp >= 1 && hp <= H) {
            const float* base = x + ((size_t)(b * 3 + c) * H + (hp - 1)) * W;
            if (m > 0) o[0] = f2b(base[8 * m - 1]);
            if (m < G - 1) {
                float4 a  = *(const float4*)(base + 8 * m);
                float4 b4 = *(const float4*)(base + 8 * m + 4);
                o[1] = f2b(a.x); o[2] = f2b(a.y); o[3] = f2b(a.z); o[4] = f2b(a.w);
                o[5] = f2b(b4.x); o[6] = f2b(b4.y); o[7] = f2b(b4.z);
            }
        }
        *(u16x8*)(P + ((size_t)(b * 4 + c) * Hp + hp) * Wp + 8 * m) = o;
    }
}

// ---------------- implicit-GEMM MFMA conv + fused BN-stats + last-block finalize ----------------
// Wave mapping: mg = wid/NG (block's 4 waves share mg), ng = wid%NG.
// bf16 output. Stats from f32 accumulators; partB[(c)*NSLOT + slot]; the last block
// (device-scope counter) stripe-reduces partB and writes ss (deterministic fixed order).
template <int Co, int CiPad, int Kp, int Hi, int Wi, int Hp, int Wp, int MT, int NT>
__global__ __launch_bounds__(256) void conv_mfma(const u16* __restrict__ inp,
                                                 const u16* __restrict__ wt,
                                                 u16* __restrict__ outb,
                                                 float* __restrict__ part,
                                                 const float* __restrict__ g,
                                                 const float* __restrict__ bbias,
                                                 float* __restrict__ ss,
                                                 u32* __restrict__ cnt,
                                                 float invN) {
    constexpr int Ho = Hi / 2, Wo = Wi / 2, HW = Ho * Wo;
    constexpr int NTile = 4 * HW;            // 64*HW/16
    constexpr int NG = NTile / NT;
    constexpr int MG = Co / 16 / MT;
    constexpr int NSLOT = NG / 4;
    constexpr int NBLK = MG * NSLOT;

    int tid = threadIdx.x;
    int wv = tid >> 6;
    int wid = blockIdx.x * 4 + wv;
    int lane = tid & 63;
    int r = lane & 15;
    int quad = lane >> 4;
    int mg = wid / NG;
    int ng = wid % NG;

    int ciq = quad >> 1;
    int kh0 = (quad & 1) * 2;

    const u16* pB[NT];
    int b_[NT], hw_[NT];
#pragma unroll
    for (int i = 0; i < NT; ++i) {
        int n = (ng * NT + i) * 16 + r;
        int b = n / HW;
        int hw = n % HW;
        int oh = hw / Wo;
        int ow = hw % Wo;
        b_[i] = b; hw_[i] = hw;
        pB[i] = inp + ((size_t)(b * CiPad + ciq) * Hp + (2 * oh + kh0)) * Wp + 2 * ow;
    }
    const u16* pA = wt + (size_t)(mg * MT * 16 + r) * Kp + quad * 8;

    f32x4 acc[MT][NT];
#pragma unroll
    for (int mt = 0; mt < MT; ++mt)
#pragma unroll
        for (int i = 0; i < NT; ++i) acc[mt][i] = (f32x4){0.f, 0.f, 0.f, 0.f};

#pragma unroll 2
    for (int kk = 0; kk < Kp / 32; ++kk) {
        bf16x8 a[MT];
#pragma unroll
        for (int mt = 0; mt < MT; ++mt)
            a[mt] = *(const bf16x8*)(pA + (size_t)mt * 16 * Kp);
#pragma unroll
        for (int i = 0; i < NT; ++i) {
            union { u32 u[4]; bf16x8 v; } bb;
            bb.u[0] = *(const u32*)(pB[i]);
            bb.u[1] = *(const u32*)(pB[i] + 2);
            bb.u[2] = *(const u32*)(pB[i] + Wp);
            bb.u[3] = *(const u32*)(pB[i] + Wp + 2);
#pragma unroll
            for (int mt = 0; mt < MT; ++mt)
                acc[mt][i] = __builtin_amdgcn_mfma_f32_16x16x32_bf16(a[mt], bb.v, acc[mt][i], 0, 0, 0);
            pB[i] += (size_t)2 * Hp * Wp;
        }
        pA += 32;
    }

#pragma unroll
    for (int mt = 0; mt < MT; ++mt) {
        int co0 = mg * MT * 16 + mt * 16 + quad * 4;
#pragma unroll
        for (int i = 0; i < NT; ++i) {
#pragma unroll
            for (int j = 0; j < 4; ++j)
                outb[((size_t)b_[i] * Co + co0 + j) * HW + hw_[i]] = f2b(acc[mt][i][j]);
        }
    }

    // ---- fused BN stats (deterministic) ----
    __shared__ float sred[4][MT * 16 * 2];
#pragma unroll
    for (int mt = 0; mt < MT; ++mt) {
#pragma unroll
        for (int j = 0; j < 4; ++j) {
            float ls1 = 0.f, ls2 = 0.f;
#pragma unroll
            for (int i = 0; i < NT; ++i) {
                float v = acc[mt][i][j];
                ls1 += v; ls2 += v * v;
            }
#pragma unroll
            for (int m = 1; m < 16; m <<= 1) {
                ls1 += __shfl_xor(ls1, m);
                ls2 += __shfl_xor(ls2, m);
            }
            if (r == 0) {
                int cl = mt * 16 + quad * 4 + j;
                sred[wv][cl * 2 + 0] = ls1;
                sred[wv][cl * 2 + 1] = ls2;
            }
        }
    }
    __syncthreads();
    int slot = blockIdx.x % NSLOT;
    int mgb  = blockIdx.x / NSLOT;
    if (tid < MT * 16) {
        float s1 = (sred[0][tid * 2] + sred[1][tid * 2]) +
                   (sred[2][tid * 2] + sred[3][tid * 2]);
        float s2 = (sred[0][tid * 2 + 1] + sred[1][tid * 2 + 1]) +
                   (sred[2][tid * 2 + 1] + sred[3][tid * 2 + 1]);
        part[((size_t)(mgb * MT * 16 + tid) * NSLOT + slot) * 2 + 0] = s1;
        part[((size_t)(mgb * MT * 16 + tid) * NSLOT + slot) * 2 + 1] = s2;
    }
    __threadfence();
    __syncthreads();
    __shared__ int elect;
    if (tid == 0) elect = (atomicAdd(cnt, 1u) == (u32)(NBLK - 1)) ? 1 : 0;
    __syncthreads();
    if (elect) {
        __threadfence();
        constexpr int SPC = 256 / Co;        // stripes per channel (Co <= 256)
        constexpr int SLEN = NSLOT / SPC;
        __shared__ float f1[256], f2[256];
        int c = tid % Co;
        int st = tid / Co;
        float s1 = 0.f, s2 = 0.f;
        for (int k = st * SLEN; k < (st + 1) * SLEN; ++k) {
            s1 += part[((size_t)c * NSLOT + k) * 2 + 0];
            s2 += part[((size_t)c * NSLOT + k) * 2 + 1];
        }
        f1[tid] = s1; f2[tid] = s2;
        __syncthreads();
        for (int h = SPC / 2; h > 0; h >>= 1) {
            if (st < h) {
                f1[st * Co + c] += f1[(st + h) * Co + c];
                f2[st * Co + c] += f2[(st + h) * Co + c];
            }
            __syncthreads();
        }
        if (tid < Co) {
            float mean = f1[tid] * invN;
            float var  = f2[tid] * invN - mean * mean;
            float inv  = rsqrtf(var + EPS);
            float sc   = inv * g[tid];
            ss[tid]      = sc;
            ss[Co + tid] = bbias[tid] - mean * sc;
        }
    }
}

// ---------------- BN apply + leaky + padded bf16 write (bf16 input) ----------------
template <int C, int H, int W>
__global__ __launch_bounds__(256) void bn_pad_v(const u16* __restrict__ in,
                                                const float* __restrict__ ss,
                                                u16* __restrict__ outp) {
    constexpr int G = W / 8 + 1;
    constexpr int Wp = 8 * G;
    constexpr int Hp = H + 2;
    int idx = blockIdx.x * 256 + threadIdx.x;
    if (idx >= 64 * C * Hp * G) return;
    int m = idx % G;
    int hp = (idx / G) % Hp;
    int c = (idx / (G * Hp)) % C;
    int b = idx / (G * Hp * C);

    u16x8 o;
#pragma unroll
    for (int i = 0; i < 8; ++i) o[i] = 0;

    if (hp >= 1 && hp <= H) {
        float sc = ss[c], sh = ss[C + c];
        const u16* base = in + ((size_t)(b * C + c) * H + (hp - 1)) * W;
        if (m > 0) o[0] = f2b(leaky(b2f(base[8 * m - 1]) * sc + sh));
        if (m < G - 1) {
            bf16x8 va = *(const bf16x8*)(base + 8 * m);
#pragma unroll
            for (int i = 0; i < 7; ++i)
                o[i + 1] = f2b(leaky(b2f((u16)va[i]) * sc + sh));
        }
    }
    *(u16x8*)(outp + ((size_t)(b * C + c) * Hp + hp) * Wp + 8 * m) = o;
}

// ---------------- L4: BN + leaky + im2col bf16 for conv5 (bf16 input) ----------------
__global__ __launch_bounds__(256) void im2col5(const u16* __restrict__ A,
                                               const float* __restrict__ ss,
                                               u16* __restrict__ ic) {
    int idx = blockIdx.x * 256 + threadIdx.x;
    if (idx >= 1472 * 1024) return;
    int k = idx & 1023;
    int n = idx >> 10;
    int b = n / 23, j = n % 23;
    int ci = k >> 2, kh = (k >> 1) & 1, kw = k & 1;
    float v = b2f(A[(size_t)b * 12288 + ci * 48 + kh * 24 + j + kw]);
    v = leaky(v * ss[ci] + ss[256 + ci]);
    ic[idx] = f2b(v);
}

// ---------------- conv5 GEMM, LDS-staged 64x64 block tile ----------------
__global__ __launch_bounds__(256) void conv5_lds(const u16* __restrict__ ic,
                                                 const u16* __restrict__ w5b,
                                                 u16* __restrict__ ic2) {
    __shared__ u16 As[64][72];
    __shared__ u16 Bs[64][72];
    int tid = threadIdx.x;
    int wv = tid >> 6;
    int lane = tid & 63;
    int r = lane & 15;
    int quad = lane >> 4;
    int gx = blockIdx.x % 23;
    int gy = blockIdx.x / 23;

    int trow = tid >> 3;
    int tcol = (tid & 7) * 8;

    f32x4 acc[2][2];
#pragma unroll
    for (int mi = 0; mi < 2; ++mi)
#pragma unroll
        for (int ni = 0; ni < 2; ++ni) acc[mi][ni] = (f32x4){0.f, 0.f, 0.f, 0.f};

    for (int ko = 0; ko < 16; ++ko) {
        int kbase = ko * 64;
        *(bf16x8*)&As[trow][tcol]      = *(const bf16x8*)(w5b + (size_t)(gy * 64 + trow) * 1024 + kbase + tcol);
        *(bf16x8*)&As[trow + 32][tcol] = *(const bf16x8*)(w5b + (size_t)(gy * 64 + trow + 32) * 1024 + kbase + tcol);
        *(bf16x8*)&Bs[trow][tcol]      = *(const bf16x8*)(ic  + (size_t)(gx * 64 + trow) * 1024 + kbase + tcol);
        *(bf16x8*)&Bs[trow + 32][tcol] = *(const bf16x8*)(ic  + (size_t)(gx * 64 + trow + 32) * 1024 + kbase + tcol);
        __syncthreads();
#pragma unroll
        for (int k2 = 0; k2 < 2; ++k2) {
            int koff = k2 * 32 + quad * 8;
            bf16x8 a0 = *(const bf16x8*)&As[(wv >> 1) * 32 + r][koff];
            bf16x8 a1 = *(const bf16x8*)&As[(wv >> 1) * 32 + 16 + r][koff];
            bf16x8 b0 = *(const bf16x8*)&Bs[(wv & 1) * 32 + r][koff];
            bf16x8 b1 = *(const bf16x8*)&Bs[(wv & 1) * 32 + 16 + r][koff];
            acc[0][0] = __builtin_amdgcn_mfma_f32_16x16x32_bf16(a0, b0, acc[0][0], 0, 0, 0);
            acc[0][1] = __builtin_amdgcn_mfma_f32_16x16x32_bf16(a0, b1, acc[0][1], 0, 0, 0);
            acc[1][0] = __builtin_amdgcn_mfma_f32_16x16x32_bf16(a1, b0, acc[1][0], 0, 0, 0);
            acc[1][1] = __builtin_amdgcn_mfma_f32_16x16x32_bf16(a1, b1, acc[1][1], 0, 0, 0);
        }
        __syncthreads();
    }

#pragma unroll
    for (int mi = 0; mi < 2; ++mi) {
#pragma unroll
        for (int ni = 0; ni < 2; ++ni) {
            int n = gx * 64 + (wv & 1) * 32 + ni * 16 + r;
            int co0 = gy * 64 + (wv >> 1) * 32 + mi * 16 + quad * 4;
            u16x4 pk;
#pragma unroll
            for (int j = 0; j < 4; ++j) pk[j] = f2b(leaky(acc[mi][ni][j]));
            *(u16x4*)(ic2 + (size_t)n * 1024 + co0) = pk;
        }
    }
}

// ---------------- linear as MFMA GEMM + sigmoid ----------------
__global__ __launch_bounds__(256) void linear_mfma(const u16* __restrict__ ic2,
                                                   const u16* __restrict__ lwb,
                                                   float* __restrict__ sig) {
    int tid = threadIdx.x;
    int wid = blockIdx.x * 4 + (tid >> 6);
    int lane = tid & 63;
    int r = lane & 15;
    int quad = lane >> 4;
    int mt = wid & 3;
    int nt = wid >> 2;

    int n = nt * 16 + r;
    const u16* pA = lwb + (size_t)(mt * 16 + r) * 1024 + quad * 8;
    const u16* pB = ic2 + (size_t)n * 1024 + quad * 8;

    f32x4 acc = {0.f, 0.f, 0.f, 0.f};
#pragma unroll 4
    for (int kk = 0; kk < 32; ++kk) {
        bf16x8 a = *(const bf16x8*)pA;
        bf16x8 bv = *(const bf16x8*)pB;
        acc = __builtin_amdgcn_mfma_f32_16x16x32_bf16(a, bv, acc, 0, 0, 0);
        pA += 32;
        pB += 32;
    }

    int b = n / 23, j = n % 23;
#pragma unroll
    for (int jj = 0; jj < 4; ++jj) {
        int o = mt * 16 + quad * 4 + jj;
        float v = 1.f / (1.f + expf(-acc[jj]));
        sig[(size_t)b * 1472 + (size_t)o * 23 + j] = v;
    }
}

// ---------------- final interleave/shuffle ----------------
__global__ void shuffle_out_kernel(const float* __restrict__ sig, float* __restrict__ out) {
    int idx = blockIdx.x * blockDim.x + threadIdx.x;
    if (idx >= 64 * 768) return;
    int o = idx % 32;
    int j = (idx / 32) % 24;
    int b = idx / 768;
    const float* s = sig + (size_t)b * 64 * 23;
    float v;
    if (j == 0)       v = s[o * 23];
    else if (j == 23) v = s[(o + 32) * 23 + 22];
    else              v = 0.5f * (s[(o + 32) * 23 + (j - 1)] + s[o * 23 + j]);
    out[idx] = v;
}

extern "C" void kernel_launch(void* const* d_in, const int* in_sizes, int n_in,
                              void* d_out, int out_size, void* d_ws, size_t ws_size,
                              hipStream_t stream) {
    (void)in_sizes; (void)n_in; (void)out_size; (void)ws_size;

    const float* x = (const float*)d_in[0];
    const float* w[5]; const float* g[5]; const float* bb[5];
    for (int i = 0; i < 5; ++i) {
        w[i]  = (const float*)d_in[1 + 3 * i];
        g[i]  = (const float*)d_in[2 + 3 * i];
        bb[i] = (const float*)d_in[3 + 3 * i];
    }
    const float* w5 = (const float*)d_in[16];
    const float* lw = (const float*)d_in[17];
    float* out = (float*)d_out;

    // ---- workspace layout (~63 MB) ----
    float* ws    = (float*)d_ws;
    u16*   A     = (u16*)ws;                    // conv-out bf16 (<= 12.6 MB)
    u16*   P     = (u16*)(ws + 6291456);        // padded inputs
    u16*   wbf   = (u16*)(ws + 13115392);       // 697,344 u16
    float* ss    = ws + 13472256;               // 512 f32
    u16*   w5b   = (u16*)(ws + 13474304);       // 1,048,576 u16
    u16*   ic    = (u16*)(ws + 13998592);       // 1,507,328 u16
    u16*   ic2   = (u16*)(ws + 14752256);       // 1,507,328 u16
    u16*   lwb   = (u16*)(ws + 15505920);       // 65,536 u16
    float* partB = ws + 15538688;               // 98,304 f32 (block-slot stats)
    u32*   cnt   = (u32*)(ws + 15636992);       // 8 u32 (layer counters)
    float* sig   = ws + 4194304;                // (64,64,23) f32 (dead region at tail time)

    const size_t wofs[5] = {0, 1024, 9216, 41984, 173056};

    hipLaunchKernelGGL(prep, dim3(13478), dim3(256), 0, stream,
                       x, w[0], w[1], w[2], w[3], w[4], w5, lw, wbf, w5b, lwb, P, cnt);

    // L0: MT=1, NT=8 -> 1536 blocks
    hipLaunchKernelGGL((conv_mfma<16, 4, 64, 64, 768, 66, 776, 1, 8>),
                       dim3(1536), dim3(256), 0, stream,
                       P, wbf + wofs[0], A, partB, g[0], bb[0], ss, cnt + 0, 1.f / 786432.f);
    hipLaunchKernelGGL((bn_pad_v<16, 32, 384>), dim3(6664), dim3(256), 0, stream, A, ss, P);

    // L1: MT=2, NT=2 -> 1536 blocks
    hipLaunchKernelGGL((conv_mfma<32, 16, 256, 32, 384, 34, 392, 2, 2>),
                       dim3(1536), dim3(256), 0, stream,
                       P, wbf + wofs[1], A, partB, g[1], bb[1], ss, cnt + 1, 1.f / 196608.f);
    hipLaunchKernelGGL((bn_pad_v<32, 16, 192>), dim3(3600), dim3(256), 0, stream, A, ss, P);

    // L2: MT=4, NT=2 -> 384 blocks
    hipLaunchKernelGGL((conv_mfma<64, 32, 512, 16, 192, 18, 200, 4, 2>),
                       dim3(384), dim3(256), 0, stream,
                       P, wbf + wofs[2], A, partB, g[2], bb[2], ss, cnt + 2, 1.f / 49152.f);
    hipLaunchKernelGGL((bn_pad_v<64, 8, 96>), dim3(2080), dim3(256), 0, stream, A, ss, P);

    // L3: MT=2 (MG=4), NT=1 -> 768 blocks
    hipLaunchKernelGGL((conv_mfma<128, 64, 1024, 8, 96, 10, 104, 2, 1>),
                       dim3(768), dim3(256), 0, stream,
                       P, wbf + wofs[3], A, partB, g[3], bb[3], ss, cnt + 3, 1.f / 12288.f);
    hipLaunchKernelGGL((bn_pad_v<128, 4, 48>), dim3(1344), dim3(256), 0, stream, A, ss, P);

    // L4: MT=2 (MG=8), NT=1 -> 384 blocks
    hipLaunchKernelGGL((conv_mfma<256, 128, 2048, 4, 48, 6, 56, 2, 1>),
                       dim3(384), dim3(256), 0, stream,
                       P, wbf + wofs[4], A, partB, g[4], bb[4], ss, cnt + 4, 1.f / 3072.f);
    hipLaunchKernelGGL(im2col5, dim3(5888), dim3(256), 0, stream, A, ss, ic);

    // tail
    hipLaunchKernelGGL(conv5_lds, dim3(368), dim3(256), 0, stream, ic, w5b, ic2);
    hipLaunchKernelGGL(linear_mfma, dim3(92), dim3(256), 0, stream, ic2, lwb, sig);
    hipLaunchKernelGGL(shuffle_out_kernel, dim3((64 * 768 + 255) / 256), dim3(256), 0, stream,
                       sig, out);
}

// Round 16
// 228.547 us; speedup vs baseline: 3.2874x; 3.2874x over previous
//
#include <hip/hip_runtime.h>
#include <cmath>

#define EPS 1e-5f
#define SLOPE 0.2f

typedef unsigned short u16;
typedef unsigned int u32;
typedef __attribute__((ext_vector_type(8))) short bf16x8;
typedef __attribute__((ext_vector_type(8))) unsigned short u16x8;
typedef __attribute__((ext_vector_type(4))) unsigned short u16x4;
typedef __attribute__((ext_vector_type(4))) float f32x4;

__device__ __forceinline__ u16 f2b(float f) {
    union { float f; u32 u; } v; v.f = f;
    u32 r = (v.u + 0x7FFF + ((v.u >> 16) & 1)) >> 16;
    return (u16)r;
}
__device__ __forceinline__ float b2f(u16 h) {
    union { u32 u; float f; } v; v.u = ((u32)h) << 16;
    return v.f;
}
__device__ __forceinline__ float leaky(float v) { return v >= 0.f ? v : SLOPE * v; }

// ---------------- fused prep: weight->bf16 converts + x padding ----------------
__global__ __launch_bounds__(256) void prep(const float* __restrict__ x,
                                            const float* __restrict__ w0,
                                            const float* __restrict__ w1,
                                            const float* __restrict__ w2,
                                            const float* __restrict__ w3,
                                            const float* __restrict__ w4,
                                            const float* __restrict__ w5,
                                            const float* __restrict__ lw,
                                            u16* __restrict__ wbf,
                                            u16* __restrict__ w5b,
                                            u16* __restrict__ lwb,
                                            u16* __restrict__ P) {
    int idx = blockIdx.x * 256 + threadIdx.x;
    if (idx < 697344) {
        const float* src; int K, Kp; int base;
        if (idx < 1024)        { src = w0; K = 48;   Kp = 64;   base = 0; }
        else if (idx < 9216)   { src = w1; K = 256;  Kp = 256;  base = 1024; }
        else if (idx < 41984)  { src = w2; K = 512;  Kp = 512;  base = 9216; }
        else if (idx < 173056) { src = w3; K = 1024; Kp = 1024; base = 41984; }
        else                   { src = w4; K = 2048; Kp = 2048; base = 173056; }
        int local = idx - base;
        int k = local % Kp;
        int co = local / Kp;
        wbf[idx] = (k < K) ? f2b(src[(size_t)co * K + k]) : (u16)0;
    } else if (idx < 1745920) {
        int local = idx - 697344;
        int k = local & 1023;
        int co = local >> 10;
        w5b[local] = (co < 1000) ? f2b(w5[(size_t)co * 1024 + k]) : (u16)0;
    } else if (idx < 1811456) {
        int local = idx - 1745920;
        int k = local & 1023;
        int o = local >> 10;
        lwb[local] = (k < 1000) ? f2b(lw[(size_t)o * 1000 + k]) : (u16)0;
    } else if (idx < 3450368) {
        constexpr int H = 64, W = 768, G = 97, Wp = 776, Hp = 66;
        int local = idx - 1811456;
        int m = local % G;
        int hp = (local / G) % Hp;
        int c = (local / (G * Hp)) % 4;
        int b = local / (G * Hp * 4);
        u16x8 o;
#pragma unroll
        for (int i = 0; i < 8; ++i) o[i] = 0;
        if (c < 3 && hp >= 1 && hp <= H) {
            const float* base = x + ((size_t)(b * 3 + c) * H + (hp - 1)) * W;
            if (m > 0) o[0] = f2b(base[8 * m - 1]);
            if (m < G - 1) {
                float4 a  = *(const float4*)(base + 8 * m);
                float4 b4 = *(const float4*)(base + 8 * m + 4);
                o[1] = f2b(a.x); o[2] = f2b(a.y); o[3] = f2b(a.z); o[4] = f2b(a.w);
                o[5] = f2b(b4.x); o[6] = f2b(b4.y); o[7] = f2b(b4.z);
            }
        }
        *(u16x8*)(P + ((size_t)(b * 4 + c) * Hp + hp) * Wp + 8 * m) = o;
    }
}

// ---------------- implicit-GEMM MFMA conv + fused BN-stats (partB slots) ----------------
// Wave mapping: mg = wid/NG (block's 4 waves share mg), ng = wid%NG. bf16 output.
// partB layout: [(mg*MT*16 + cl)][NSLOT] float pairs; finalize in bn_finalize_blk.
template <int Co, int CiPad, int Kp, int Hi, int Wi, int Hp, int Wp, int MT, int NT>
__global__ __launch_bounds__(256) void conv_mfma(const u16* __restrict__ inp,
                                                 const u16* __restrict__ wt,
                                                 u16* __restrict__ outb,
                                                 float* __restrict__ part) {
    constexpr int Ho = Hi / 2, Wo = Wi / 2, HW = Ho * Wo;
    constexpr int NTile = 4 * HW;
    constexpr int NG = NTile / NT;
    constexpr int NSLOT = NG / 4;

    int tid = threadIdx.x;
    int wv = tid >> 6;
    int wid = blockIdx.x * 4 + wv;
    int lane = tid & 63;
    int r = lane & 15;
    int quad = lane >> 4;
    int mg = wid / NG;
    int ng = wid % NG;

    int ciq = quad >> 1;
    int kh0 = (quad & 1) * 2;

    const u16* pB[NT];
    int b_[NT], hw_[NT];
#pragma unroll
    for (int i = 0; i < NT; ++i) {
        int n = (ng * NT + i) * 16 + r;
        int b = n / HW;
        int hw = n % HW;
        int oh = hw / Wo;
        int ow = hw % Wo;
        b_[i] = b; hw_[i] = hw;
        pB[i] = inp + ((size_t)(b * CiPad + ciq) * Hp + (2 * oh + kh0)) * Wp + 2 * ow;
    }
    const u16* pA = wt + (size_t)(mg * MT * 16 + r) * Kp + quad * 8;

    f32x4 acc[MT][NT];
#pragma unroll
    for (int mt = 0; mt < MT; ++mt)
#pragma unroll
        for (int i = 0; i < NT; ++i) acc[mt][i] = (f32x4){0.f, 0.f, 0.f, 0.f};

#pragma unroll 2
    for (int kk = 0; kk < Kp / 32; ++kk) {
        bf16x8 a[MT];
#pragma unroll
        for (int mt = 0; mt < MT; ++mt)
            a[mt] = *(const bf16x8*)(pA + (size_t)mt * 16 * Kp);
#pragma unroll
        for (int i = 0; i < NT; ++i) {
            union { u32 u[4]; bf16x8 v; } bb;
            bb.u[0] = *(const u32*)(pB[i]);
            bb.u[1] = *(const u32*)(pB[i] + 2);
            bb.u[2] = *(const u32*)(pB[i] + Wp);
            bb.u[3] = *(const u32*)(pB[i] + Wp + 2);
#pragma unroll
            for (int mt = 0; mt < MT; ++mt)
                acc[mt][i] = __builtin_amdgcn_mfma_f32_16x16x32_bf16(a[mt], bb.v, acc[mt][i], 0, 0, 0);
            pB[i] += (size_t)2 * Hp * Wp;
        }
        pA += 32;
    }

#pragma unroll
    for (int mt = 0; mt < MT; ++mt) {
        int co0 = mg * MT * 16 + mt * 16 + quad * 4;
#pragma unroll
        for (int i = 0; i < NT; ++i) {
#pragma unroll
            for (int j = 0; j < 4; ++j)
                outb[((size_t)b_[i] * Co + co0 + j) * HW + hw_[i]] = f2b(acc[mt][i][j]);
        }
    }

    // ---- fused BN stats (deterministic; no fences, no atomics) ----
    __shared__ float sred[4][MT * 16 * 2];
#pragma unroll
    for (int mt = 0; mt < MT; ++mt) {
#pragma unroll
        for (int j = 0; j < 4; ++j) {
            float ls1 = 0.f, ls2 = 0.f;
#pragma unroll
            for (int i = 0; i < NT; ++i) {
                float v = acc[mt][i][j];
                ls1 += v; ls2 += v * v;
            }
#pragma unroll
            for (int m = 1; m < 16; m <<= 1) {
                ls1 += __shfl_xor(ls1, m);
                ls2 += __shfl_xor(ls2, m);
            }
            if (r == 0) {
                int cl = mt * 16 + quad * 4 + j;
                sred[wv][cl * 2 + 0] = ls1;
                sred[wv][cl * 2 + 1] = ls2;
            }
        }
    }
    __syncthreads();
    int slot = blockIdx.x % NSLOT;
    int mgb  = blockIdx.x / NSLOT;
    if (tid < MT * 16) {
        float s1 = (sred[0][tid * 2] + sred[1][tid * 2]) +
                   (sred[2][tid * 2] + sred[3][tid * 2]);
        float s2 = (sred[0][tid * 2 + 1] + sred[1][tid * 2 + 1]) +
                   (sred[2][tid * 2 + 1] + sred[3][tid * 2 + 1]);
        part[((size_t)(mgb * MT * 16 + tid) * NSLOT + slot) * 2 + 0] = s1;
        part[((size_t)(mgb * MT * 16 + tid) * NSLOT + slot) * 2 + 1] = s2;
    }
}

// ---------------- per-channel finalize: part[C][NSLOT] -> ss ----------------
template <int C, int NSLOT>
__global__ __launch_bounds__(256) void bn_finalize_blk(const float* __restrict__ part,
                                                       const float* __restrict__ g,
                                                       const float* __restrict__ bb,
                                                       float* __restrict__ ss, float invN) {
    int c = blockIdx.x;
    int tid = threadIdx.x;
    float s1 = 0.f, s2 = 0.f;
    for (int k = tid; k < NSLOT; k += 256) {
        s1 += part[((size_t)c * NSLOT + k) * 2 + 0];
        s2 += part[((size_t)c * NSLOT + k) * 2 + 1];
    }
    __shared__ float sh1[256], sh2[256];
    sh1[tid] = s1; sh2[tid] = s2;
    __syncthreads();
    for (int s = 128; s > 0; s >>= 1) {
        if (tid < s) { sh1[tid] += sh1[tid + s]; sh2[tid] += sh2[tid + s]; }
        __syncthreads();
    }
    if (tid == 0) {
        float mean = sh1[0] * invN;
        float var  = sh2[0] * invN - mean * mean;
        float inv  = rsqrtf(var + EPS);
        float sc   = inv * g[c];
        ss[c]     = sc;
        ss[C + c] = bb[c] - mean * sc;
    }
}

// ---------------- BN apply + leaky + padded bf16 write (bf16 input) ----------------
template <int C, int H, int W>
__global__ __launch_bounds__(256) void bn_pad_v(const u16* __restrict__ in,
                                                const float* __restrict__ ss,
                                                u16* __restrict__ outp) {
    constexpr int G = W / 8 + 1;
    constexpr int Wp = 8 * G;
    constexpr int Hp = H + 2;
    int idx = blockIdx.x * 256 + threadIdx.x;
    if (idx >= 64 * C * Hp * G) return;
    int m = idx % G;
    int hp = (idx / G) % Hp;
    int c = (idx / (G * Hp)) % C;
    int b = idx / (G * Hp * C);

    u16x8 o;
#pragma unroll
    for (int i = 0; i < 8; ++i) o[i] = 0;

    if (hp >= 1 && hp <= H) {
        float sc = ss[c], sh = ss[C + c];
        const u16* base = in + ((size_t)(b * C + c) * H + (hp - 1)) * W;
        if (m > 0) o[0] = f2b(leaky(b2f(base[8 * m - 1]) * sc + sh));
        if (m < G - 1) {
            bf16x8 va = *(const bf16x8*)(base + 8 * m);
#pragma unroll
            for (int i = 0; i < 7; ++i)
                o[i + 1] = f2b(leaky(b2f((u16)va[i]) * sc + sh));
        }
    }
    *(u16x8*)(outp + ((size_t)(b * C + c) * Hp + hp) * Wp + 8 * m) = o;
}

// ---------------- L4: BN + leaky + im2col bf16 for conv5 (bf16 input) ----------------
__global__ __launch_bounds__(256) void im2col5(const u16* __restrict__ A,
                                               const float* __restrict__ ss,
                                               u16* __restrict__ ic) {
    int idx = blockIdx.x * 256 + threadIdx.x;
    if (idx >= 1472 * 1024) return;
    int k = idx & 1023;
    int n = idx >> 10;
    int b = n / 23, j = n % 23;
    int ci = k >> 2, kh = (k >> 1) & 1, kw = k & 1;
    float v = b2f(A[(size_t)b * 12288 + ci * 48 + kh * 24 + j + kw]);
    v = leaky(v * ss[ci] + ss[256 + ci]);
    ic[idx] = f2b(v);
}

// ---------------- conv5 GEMM, LDS-staged 64x64 block tile ----------------
__global__ __launch_bounds__(256) void conv5_lds(const u16* __restrict__ ic,
                                                 const u16* __restrict__ w5b,
                                                 u16* __restrict__ ic2) {
    __shared__ u16 As[64][72];
    __shared__ u16 Bs[64][72];
    int tid = threadIdx.x;
    int wv = tid >> 6;
    int lane = tid & 63;
    int r = lane & 15;
    int quad = lane >> 4;
    int gx = blockIdx.x % 23;
    int gy = blockIdx.x / 23;

    int trow = tid >> 3;
    int tcol = (tid & 7) * 8;

    f32x4 acc[2][2];
#pragma unroll
    for (int mi = 0; mi < 2; ++mi)
#pragma unroll
        for (int ni = 0; ni < 2; ++ni) acc[mi][ni] = (f32x4){0.f, 0.f, 0.f, 0.f};

    for (int ko = 0; ko < 16; ++ko) {
        int kbase = ko * 64;
        *(bf16x8*)&As[trow][tcol]      = *(const bf16x8*)(w5b + (size_t)(gy * 64 + trow) * 1024 + kbase + tcol);
        *(bf16x8*)&As[trow + 32][tcol] = *(const bf16x8*)(w5b + (size_t)(gy * 64 + trow + 32) * 1024 + kbase + tcol);
        *(bf16x8*)&Bs[trow][tcol]      = *(const bf16x8*)(ic  + (size_t)(gx * 64 + trow) * 1024 + kbase + tcol);
        *(bf16x8*)&Bs[trow + 32][tcol] = *(const bf16x8*)(ic  + (size_t)(gx * 64 + trow + 32) * 1024 + kbase + tcol);
        __syncthreads();
#pragma unroll
        for (int k2 = 0; k2 < 2; ++k2) {
            int koff = k2 * 32 + quad * 8;
            bf16x8 a0 = *(const bf16x8*)&As[(wv >> 1) * 32 + r][koff];
            bf16x8 a1 = *(const bf16x8*)&As[(wv >> 1) * 32 + 16 + r][koff];
            bf16x8 b0 = *(const bf16x8*)&Bs[(wv & 1) * 32 + r][koff];
            bf16x8 b1 = *(const bf16x8*)&Bs[(wv & 1) * 32 + 16 + r][koff];
            acc[0][0] = __builtin_amdgcn_mfma_f32_16x16x32_bf16(a0, b0, acc[0][0], 0, 0, 0);
            acc[0][1] = __builtin_amdgcn_mfma_f32_16x16x32_bf16(a0, b1, acc[0][1], 0, 0, 0);
            acc[1][0] = __builtin_amdgcn_mfma_f32_16x16x32_bf16(a1, b0, acc[1][0], 0, 0, 0);
            acc[1][1] = __builtin_amdgcn_mfma_f32_16x16x32_bf16(a1, b1, acc[1][1], 0, 0, 0);
        }
        __syncthreads();
    }

#pragma unroll
    for (int mi = 0; mi < 2; ++mi) {
#pragma unroll
        for (int ni = 0; ni < 2; ++ni) {
            int n = gx * 64 + (wv & 1) * 32 + ni * 16 + r;
            int co0 = gy * 64 + (wv >> 1) * 32 + mi * 16 + quad * 4;
            u16x4 pk;
#pragma unroll
            for (int j = 0; j < 4; ++j) pk[j] = f2b(leaky(acc[mi][ni][j]));
            *(u16x4*)(ic2 + (size_t)n * 1024 + co0) = pk;
        }
    }
}

// ---------------- linear as MFMA GEMM + sigmoid ----------------
__global__ __launch_bounds__(256) void linear_mfma(const u16* __restrict__ ic2,
                                                   const u16* __restrict__ lwb,
                                                   float* __restrict__ sig) {
    int tid = threadIdx.x;
    int wid = blockIdx.x * 4 + (tid >> 6);
    int lane = tid & 63;
    int r = lane & 15;
    int quad = lane >> 4;
    int mt = wid & 3;
    int nt = wid >> 2;

    int n = nt * 16 + r;
    const u16* pA = lwb + (size_t)(mt * 16 + r) * 1024 + quad * 8;
    const u16* pB = ic2 + (size_t)n * 1024 + quad * 8;

    f32x4 acc = {0.f, 0.f, 0.f, 0.f};
#pragma unroll 4
    for (int kk = 0; kk < 32; ++kk) {
        bf16x8 a = *(const bf16x8*)pA;
        bf16x8 bv = *(const bf16x8*)pB;
        acc = __builtin_amdgcn_mfma_f32_16x16x32_bf16(a, bv, acc, 0, 0, 0);
        pA += 32;
        pB += 32;
    }

    int b = n / 23, j = n % 23;
#pragma unroll
    for (int jj = 0; jj < 4; ++jj) {
        int o = mt * 16 + quad * 4 + jj;
        float v = 1.f / (1.f + expf(-acc[jj]));
        sig[(size_t)b * 1472 + (size_t)o * 23 + j] = v;
    }
}

// ---------------- final interleave/shuffle ----------------
__global__ void shuffle_out_kernel(const float* __restrict__ sig, float* __restrict__ out) {
    int idx = blockIdx.x * blockDim.x + threadIdx.x;
    if (idx >= 64 * 768) return;
    int o = idx % 32;
    int j = (idx / 32) % 24;
    int b = idx / 768;
    const float* s = sig + (size_t)b * 64 * 23;
    float v;
    if (j == 0)       v = s[o * 23];
    else if (j == 23) v = s[(o + 32) * 23 + 22];
    else              v = 0.5f * (s[(o + 32) * 23 + (j - 1)] + s[o * 23 + j]);
    out[idx] = v;
}

extern "C" void kernel_launch(void* const* d_in, const int* in_sizes, int n_in,
                              void* d_out, int out_size, void* d_ws, size_t ws_size,
                              hipStream_t stream) {
    (void)in_sizes; (void)n_in; (void)out_size; (void)ws_size;

    const float* x = (const float*)d_in[0];
    const float* w[5]; const float* g[5]; const float* bb[5];
    for (int i = 0; i < 5; ++i) {
        w[i]  = (const float*)d_in[1 + 3 * i];
        g[i]  = (const float*)d_in[2 + 3 * i];
        bb[i] = (const float*)d_in[3 + 3 * i];
    }
    const float* w5 = (const float*)d_in[16];
    const float* lw = (const float*)d_in[17];
    float* out = (float*)d_out;

    // ---- workspace layout (~63 MB) ----
    float* ws    = (float*)d_ws;
    u16*   A     = (u16*)ws;                    // conv-out bf16 (<= 25 MB for L0)
    u16*   P     = (u16*)(ws + 6291456);        // padded inputs
    u16*   wbf   = (u16*)(ws + 13115392);       // 697,344 u16
    float* ss    = ws + 13472256;               // 512 f32
    u16*   w5b   = (u16*)(ws + 13474304);       // 1,048,576 u16
    u16*   ic    = (u16*)(ws + 13998592);       // 1,507,328 u16
    u16*   ic2   = (u16*)(ws + 14752256);       // 1,507,328 u16
    u16*   lwb   = (u16*)(ws + 15505920);       // 65,536 u16
    float* partB = ws + 15538688;               // 98,304 f32 (block-slot stats)
    float* sig   = ws + 4194304;                // (64,64,23) f32 (dead region at tail time)

    const size_t wofs[5] = {0, 1024, 9216, 41984, 173056};

    hipLaunchKernelGGL(prep, dim3(13478), dim3(256), 0, stream,
                       x, w[0], w[1], w[2], w[3], w[4], w5, lw, wbf, w5b, lwb, P);

    // L0: MT=1, NT=8 -> 1536 blocks, NSLOT=1536
    hipLaunchKernelGGL((conv_mfma<16, 4, 64, 64, 768, 66, 776, 1, 8>),
                       dim3(1536), dim3(256), 0, stream, P, wbf + wofs[0], A, partB);
    hipLaunchKernelGGL((bn_finalize_blk<16, 1536>), dim3(16), dim3(256), 0, stream,
                       partB, g[0], bb[0], ss, 1.f / 786432.f);
    hipLaunchKernelGGL((bn_pad_v<16, 32, 384>), dim3(6664), dim3(256), 0, stream, A, ss, P);

    // L1: MT=2, NT=2 -> 1536 blocks, NSLOT=1536
    hipLaunchKernelGGL((conv_mfma<32, 16, 256, 32, 384, 34, 392, 2, 2>),
                       dim3(1536), dim3(256), 0, stream, P, wbf + wofs[1], A, partB);
    hipLaunchKernelGGL((bn_finalize_blk<32, 1536>), dim3(32), dim3(256), 0, stream,
                       partB, g[1], bb[1], ss, 1.f / 196608.f);
    hipLaunchKernelGGL((bn_pad_v<32, 16, 192>), dim3(3600), dim3(256), 0, stream, A, ss, P);

    // L2: MT=4, NT=2 -> 384 blocks, NSLOT=384
    hipLaunchKernelGGL((conv_mfma<64, 32, 512, 16, 192, 18, 200, 4, 2>),
                       dim3(384), dim3(256), 0, stream, P, wbf + wofs[2], A, partB);
    hipLaunchKernelGGL((bn_finalize_blk<64, 384>), dim3(64), dim3(256), 0, stream,
                       partB, g[2], bb[2], ss, 1.f / 49152.f);
    hipLaunchKernelGGL((bn_pad_v<64, 8, 96>), dim3(2080), dim3(256), 0, stream, A, ss, P);

    // L3: MT=2 (MG=4), NT=1 -> 768 blocks, NSLOT=192
    hipLaunchKernelGGL((conv_mfma<128, 64, 1024, 8, 96, 10, 104, 2, 1>),
                       dim3(768), dim3(256), 0, stream, P, wbf + wofs[3], A, partB);
    hipLaunchKernelGGL((bn_finalize_blk<128, 192>), dim3(128), dim3(256), 0, stream,
                       partB, g[3], bb[3], ss, 1.f / 12288.f);
    hipLaunchKernelGGL((bn_pad_v<128, 4, 48>), dim3(1344), dim3(256), 0, stream, A, ss, P);

    // L4: MT=2 (MG=8), NT=1 -> 384 blocks, NSLOT=48
    hipLaunchKernelGGL((conv_mfma<256, 128, 2048, 4, 48, 6, 56, 2, 1>),
                       dim3(384), dim3(256), 0, stream, P, wbf + wofs[4], A, partB);
    hipLaunchKernelGGL((bn_finalize_blk<256, 48>), dim3(256), dim3(256), 0, stream,
                       partB, g[4], bb[4], ss, 1.f / 3072.f);
    hipLaunchKernelGGL(im2col5, dim3(5888), dim3(256), 0, stream, A, ss, ic);

    // tail
    hipLaunchKernelGGL(conv5_lds, dim3(368), dim3(256), 0, stream, ic, w5b, ic2);
    hipLaunchKernelGGL(linear_mfma, dim3(92), dim3(256), 0, stream, ic2, lwb, sig);
    hipLaunchKernelGGL(shuffle_out_kernel, dim3((64 * 768 + 255) / 256), dim3(256), 0, stream,
                       sig, out);
}

// Round 17
// 176.582 us; speedup vs baseline: 4.2548x; 1.2943x over previous
//
#include <hip/hip_runtime.h>
#include <cmath>

#define EPS 1e-5f
#define SLOPE 0.2f

typedef unsigned short u16;
typedef unsigned int u32;
typedef __attribute__((ext_vector_type(8))) short bf16x8;
typedef __attribute__((ext_vector_type(8))) unsigned short u16x8;
typedef __attribute__((ext_vector_type(4))) unsigned short u16x4;
typedef __attribute__((ext_vector_type(4))) float f32x4;

__device__ __forceinline__ u16 f2b(float f) {
    union { float f; u32 u; } v; v.f = f;
    u32 r = (v.u + 0x7FFF + ((v.u >> 16) & 1)) >> 16;
    return (u16)r;
}
__device__ __forceinline__ float b2f(u16 h) {
    union { u32 u; float f; } v; v.u = ((u32)h) << 16;
    return v.f;
}
__device__ __forceinline__ float leaky(float v) { return v >= 0.f ? v : SLOPE * v; }

// ---------------- fused prep: weight->bf16 (K-major tiled layout) + x padding ----------------
// Weight layout per 16-row m-tile: [kb][quad][r][8] (kb = k/32, quad = (k%32)/8).
// A-load address = tile_base + kb*512 + quad*128 + r*8  ->  wave reads 1024B contiguous.
__global__ __launch_bounds__(256) void prep(const float* __restrict__ x,
                                            const float* __restrict__ w0,
                                            const float* __restrict__ w1,
                                            const float* __restrict__ w2,
                                            const float* __restrict__ w3,
                                            const float* __restrict__ w4,
                                            const float* __restrict__ w5,
                                            const float* __restrict__ lw,
                                            u16* __restrict__ wbf,
                                            u16* __restrict__ w5b,
                                            u16* __restrict__ lwb,
                                            u16* __restrict__ P) {
    int idx = blockIdx.x * 256 + threadIdx.x;
    if (idx < 697344) {
        const float* src; int K, lgn, base;
        if (idx < 1024)        { src = w0; K = 48;   lgn = 1; base = 0; }       // Kp=64
        else if (idx < 9216)   { src = w1; K = 256;  lgn = 3; base = 1024; }    // Kp=256
        else if (idx < 41984)  { src = w2; K = 512;  lgn = 4; base = 9216; }    // Kp=512
        else if (idx < 173056) { src = w3; K = 1024; lgn = 5; base = 41984; }   // Kp=1024
        else                   { src = w4; K = 2048; lgn = 6; base = 173056; }  // Kp=2048
        int local = idx - base;
        int e = local & 7;
        int r = (local >> 3) & 15;
        int q = (local >> 7) & 3;
        int rest = local >> 9;
        int kb = rest & ((1 << lgn) - 1);
        int tm = rest >> lgn;
        int co = tm * 16 + r;
        int k  = kb * 32 + q * 8 + e;
        wbf[idx] = (k < K) ? f2b(src[(size_t)co * K + k]) : (u16)0;
    } else if (idx < 1745920) {
        int local = idx - 697344;
        int k = local & 1023;
        int co = local >> 10;
        w5b[local] = (co < 1000) ? f2b(w5[(size_t)co * 1024 + k]) : (u16)0;
    } else if (idx < 1811456) {
        // lw -> K-major tiled layout (Kp=1024, nkb=32)
        int local = idx - 1745920;
        int e = local & 7;
        int r = (local >> 3) & 15;
        int q = (local >> 7) & 3;
        int rest = local >> 9;
        int kb = rest & 31;
        int tm = rest >> 5;
        int o = tm * 16 + r;
        int k = kb * 32 + q * 8 + e;
        lwb[local] = (k < 1000) ? f2b(lw[(size_t)o * 1000 + k]) : (u16)0;
    } else if (idx < 3450368) {
        constexpr int H = 64, W = 768, G = 97, Wp = 776, Hp = 66;
        int local = idx - 1811456;
        int m = local % G;
        int hp = (local / G) % Hp;
        int c = (local / (G * Hp)) % 4;
        int b = local / (G * Hp * 4);
        u16x8 o;
#pragma unroll
        for (int i = 0; i < 8; ++i) o[i] = 0;
        if (c < 3 && hp >= 1 && hp <= H) {
            const float* base = x + ((size_t)(b * 3 + c) * H + (hp - 1)) * W;
            if (m > 0) o[0] = f2b(base[8 * m - 1]);
            if (m < G - 1) {
                float4 a  = *(const float4*)(base + 8 * m);
                float4 b4 = *(const float4*)(base + 8 * m + 4);
                o[1] = f2b(a.x); o[2] = f2b(a.y); o[3] = f2b(a.z); o[4] = f2b(a.w);
                o[5] = f2b(b4.x); o[6] = f2b(b4.y); o[7] = f2b(b4.z);
            }
        }
        *(u16x8*)(P + ((size_t)(b * 4 + c) * Hp + hp) * Wp + 8 * m) = o;
    }
}

// ---------------- implicit-GEMM MFMA conv + fused BN-stats (partB slots) ----------------
// Wave mapping: mg = wid/NG, ng = wid%NG. bf16 output. Weights in K-major tiled layout.
template <int Co, int CiPad, int Kp, int Hi, int Wi, int Hp, int Wp, int MT, int NT>
__global__ __launch_bounds__(256) void conv_mfma(const u16* __restrict__ inp,
                                                 const u16* __restrict__ wt,
                                                 u16* __restrict__ outb,
                                                 float* __restrict__ part) {
    constexpr int Ho = Hi / 2, Wo = Wi / 2, HW = Ho * Wo;
    constexpr int NTile = 4 * HW;
    constexpr int NG = NTile / NT;
    constexpr int NSLOT = NG / 4;

    int tid = threadIdx.x;
    int wv = tid >> 6;
    int wid = blockIdx.x * 4 + wv;
    int lane = tid & 63;
    int r = lane & 15;
    int quad = lane >> 4;
    int mg = wid / NG;
    int ng = wid % NG;

    int ciq = quad >> 1;
    int kh0 = (quad & 1) * 2;

    const u16* pB[NT];
    int b_[NT], hw_[NT];
#pragma unroll
    for (int i = 0; i < NT; ++i) {
        int n = (ng * NT + i) * 16 + r;
        int b = n / HW;
        int hw = n % HW;
        int oh = hw / Wo;
        int ow = hw % Wo;
        b_[i] = b; hw_[i] = hw;
        pB[i] = inp + ((size_t)(b * CiPad + ciq) * Hp + (2 * oh + kh0)) * Wp + 2 * ow;
    }
    // K-major tiled A: tile (mg*MT+mt) base = tile*16*Kp; per kk advance 512.
    const u16* pA = wt + (size_t)(mg * MT) * 16 * Kp + quad * 128 + r * 8;

    f32x4 acc[MT][NT];
#pragma unroll
    for (int mt = 0; mt < MT; ++mt)
#pragma unroll
        for (int i = 0; i < NT; ++i) acc[mt][i] = (f32x4){0.f, 0.f, 0.f, 0.f};

#pragma unroll 2
    for (int kk = 0; kk < Kp / 32; ++kk) {
        bf16x8 a[MT];
#pragma unroll
        for (int mt = 0; mt < MT; ++mt)
            a[mt] = *(const bf16x8*)(pA + (size_t)mt * 16 * Kp);
#pragma unroll
        for (int i = 0; i < NT; ++i) {
            union { u32 u[4]; bf16x8 v; } bb;
            bb.u[0] = *(const u32*)(pB[i]);
            bb.u[1] = *(const u32*)(pB[i] + 2);
            bb.u[2] = *(const u32*)(pB[i] + Wp);
            bb.u[3] = *(const u32*)(pB[i] + Wp + 2);
#pragma unroll
            for (int mt = 0; mt < MT; ++mt)
                acc[mt][i] = __builtin_amdgcn_mfma_f32_16x16x32_bf16(a[mt], bb.v, acc[mt][i], 0, 0, 0);
            pB[i] += (size_t)2 * Hp * Wp;
        }
        pA += 512;
    }

#pragma unroll
    for (int mt = 0; mt < MT; ++mt) {
        int co0 = mg * MT * 16 + mt * 16 + quad * 4;
#pragma unroll
        for (int i = 0; i < NT; ++i) {
#pragma unroll
            for (int j = 0; j < 4; ++j)
                outb[((size_t)b_[i] * Co + co0 + j) * HW + hw_[i]] = f2b(acc[mt][i][j]);
        }
    }

    // ---- fused BN stats (deterministic; no fences, no atomics) ----
    __shared__ float sred[4][MT * 16 * 2];
#pragma unroll
    for (int mt = 0; mt < MT; ++mt) {
#pragma unroll
        for (int j = 0; j < 4; ++j) {
            float ls1 = 0.f, ls2 = 0.f;
#pragma unroll
            for (int i = 0; i < NT; ++i) {
                float v = acc[mt][i][j];
                ls1 += v; ls2 += v * v;
            }
#pragma unroll
            for (int m = 1; m < 16; m <<= 1) {
                ls1 += __shfl_xor(ls1, m);
                ls2 += __shfl_xor(ls2, m);
            }
            if (r == 0) {
                int cl = mt * 16 + quad * 4 + j;
                sred[wv][cl * 2 + 0] = ls1;
                sred[wv][cl * 2 + 1] = ls2;
            }
        }
    }
    __syncthreads();
    int slot = blockIdx.x % NSLOT;
    int mgb  = blockIdx.x / NSLOT;
    if (tid < MT * 16) {
        float s1 = (sred[0][tid * 2] + sred[1][tid * 2]) +
                   (sred[2][tid * 2] + sred[3][tid * 2]);
        float s2 = (sred[0][tid * 2 + 1] + sred[1][tid * 2 + 1]) +
                   (sred[2][tid * 2 + 1] + sred[3][tid * 2 + 1]);
        part[((size_t)(mgb * MT * 16 + tid) * NSLOT + slot) * 2 + 0] = s1;
        part[((size_t)(mgb * MT * 16 + tid) * NSLOT + slot) * 2 + 1] = s2;
    }
}

// ---------------- per-channel finalize: part[C][NSLOT] -> ss ----------------
template <int C, int NSLOT>
__global__ __launch_bounds__(256) void bn_finalize_blk(const float* __restrict__ part,
                                                       const float* __restrict__ g,
                                                       const float* __restrict__ bb,
                                                       float* __restrict__ ss, float invN) {
    int c = blockIdx.x;
    int tid = threadIdx.x;
    float s1 = 0.f, s2 = 0.f;
    for (int k = tid; k < NSLOT; k += 256) {
        s1 += part[((size_t)c * NSLOT + k) * 2 + 0];
        s2 += part[((size_t)c * NSLOT + k) * 2 + 1];
    }
    __shared__ float sh1[256], sh2[256];
    sh1[tid] = s1; sh2[tid] = s2;
    __syncthreads();
    for (int s = 128; s > 0; s >>= 1) {
        if (tid < s) { sh1[tid] += sh1[tid + s]; sh2[tid] += sh2[tid + s]; }
        __syncthreads();
    }
    if (tid == 0) {
        float mean = sh1[0] * invN;
        float var  = sh2[0] * invN - mean * mean;
        float inv  = rsqrtf(var + EPS);
        float sc   = inv * g[c];
        ss[c]     = sc;
        ss[C + c] = bb[c] - mean * sc;
    }
}

// ---------------- BN apply + leaky + padded bf16 write (bf16 input) ----------------
template <int C, int H, int W>
__global__ __launch_bounds__(256) void bn_pad_v(const u16* __restrict__ in,
                                                const float* __restrict__ ss,
                                                u16* __restrict__ outp) {
    constexpr int G = W / 8 + 1;
    constexpr int Wp = 8 * G;
    constexpr int Hp = H + 2;
    int idx = blockIdx.x * 256 + threadIdx.x;
    if (idx >= 64 * C * Hp * G) return;
    int m = idx % G;
    int hp = (idx / G) % Hp;
    int c = (idx / (G * Hp)) % C;
    int b = idx / (G * Hp * C);

    u16x8 o;
#pragma unroll
    for (int i = 0; i < 8; ++i) o[i] = 0;

    if (hp >= 1 && hp <= H) {
        float sc = ss[c], sh = ss[C + c];
        const u16* base = in + ((size_t)(b * C + c) * H + (hp - 1)) * W;
        if (m > 0) o[0] = f2b(leaky(b2f(base[8 * m - 1]) * sc + sh));
        if (m < G - 1) {
            bf16x8 va = *(const bf16x8*)(base + 8 * m);
#pragma unroll
            for (int i = 0; i < 7; ++i)
                o[i + 1] = f2b(leaky(b2f((u16)va[i]) * sc + sh));
        }
    }
    *(u16x8*)(outp + ((size_t)(b * C + c) * Hp + hp) * Wp + 8 * m) = o;
}

// ---------------- L4: BN + leaky + im2col bf16 for conv5 (bf16 input) ----------------
__global__ __launch_bounds__(256) void im2col5(const u16* __restrict__ A,
                                               const float* __restrict__ ss,
                                               u16* __restrict__ ic) {
    int idx = blockIdx.x * 256 + threadIdx.x;
    if (idx >= 1472 * 1024) return;
    int k = idx & 1023;
    int n = idx >> 10;
    int b = n / 23, j = n % 23;
    int ci = k >> 2, kh = (k >> 1) & 1, kw = k & 1;
    float v = b2f(A[(size_t)b * 12288 + ci * 48 + kh * 24 + j + kw]);
    v = leaky(v * ss[ci] + ss[256 + ci]);
    ic[idx] = f2b(v);
}

// ---------------- conv5 GEMM, LDS-staged 64x64 block tile ----------------
__global__ __launch_bounds__(256) void conv5_lds(const u16* __restrict__ ic,
                                                 const u16* __restrict__ w5b,
                                                 u16* __restrict__ ic2) {
    __shared__ u16 As[64][72];
    __shared__ u16 Bs[64][72];
    int tid = threadIdx.x;
    int wv = tid >> 6;
    int lane = tid & 63;
    int r = lane & 15;
    int quad = lane >> 4;
    int gx = blockIdx.x % 23;
    int gy = blockIdx.x / 23;

    int trow = tid >> 3;
    int tcol = (tid & 7) * 8;

    f32x4 acc[2][2];
#pragma unroll
    for (int mi = 0; mi < 2; ++mi)
#pragma unroll
        for (int ni = 0; ni < 2; ++ni) acc[mi][ni] = (f32x4){0.f, 0.f, 0.f, 0.f};

    for (int ko = 0; ko < 16; ++ko) {
        int kbase = ko * 64;
        *(bf16x8*)&As[trow][tcol]      = *(const bf16x8*)(w5b + (size_t)(gy * 64 + trow) * 1024 + kbase + tcol);
        *(bf16x8*)&As[trow + 32][tcol] = *(const bf16x8*)(w5b + (size_t)(gy * 64 + trow + 32) * 1024 + kbase + tcol);
        *(bf16x8*)&Bs[trow][tcol]      = *(const bf16x8*)(ic  + (size_t)(gx * 64 + trow) * 1024 + kbase + tcol);
        *(bf16x8*)&Bs[trow + 32][tcol] = *(const bf16x8*)(ic  + (size_t)(gx * 64 + trow + 32) * 1024 + kbase + tcol);
        __syncthreads();
#pragma unroll
        for (int k2 = 0; k2 < 2; ++k2) {
            int koff = k2 * 32 + quad * 8;
            bf16x8 a0 = *(const bf16x8*)&As[(wv >> 1) * 32 + r][koff];
            bf16x8 a1 = *(const bf16x8*)&As[(wv >> 1) * 32 + 16 + r][koff];
            bf16x8 b0 = *(const bf16x8*)&Bs[(wv & 1) * 32 + r][koff];
            bf16x8 b1 = *(const bf16x8*)&Bs[(wv & 1) * 32 + 16 + r][koff];
            acc[0][0] = __builtin_amdgcn_mfma_f32_16x16x32_bf16(a0, b0, acc[0][0], 0, 0, 0);
            acc[0][1] = __builtin_amdgcn_mfma_f32_16x16x32_bf16(a0, b1, acc[0][1], 0, 0, 0);
            acc[1][0] = __builtin_amdgcn_mfma_f32_16x16x32_bf16(a1, b0, acc[1][0], 0, 0, 0);
            acc[1][1] = __builtin_amdgcn_mfma_f32_16x16x32_bf16(a1, b1, acc[1][1], 0, 0, 0);
        }
        __syncthreads();
    }

#pragma unroll
    for (int mi = 0; mi < 2; ++mi) {
#pragma unroll
        for (int ni = 0; ni < 2; ++ni) {
            int n = gx * 64 + (wv & 1) * 32 + ni * 16 + r;
            int co0 = gy * 64 + (wv >> 1) * 32 + mi * 16 + quad * 4;
            u16x4 pk;
#pragma unroll
            for (int j = 0; j < 4; ++j) pk[j] = f2b(leaky(acc[mi][ni][j]));
            *(u16x4*)(ic2 + (size_t)n * 1024 + co0) = pk;
        }
    }
}

// ---------------- linear as MFMA GEMM + sigmoid (A in K-major tiled layout) ----------------
__global__ __launch_bounds__(256) void linear_mfma(const u16* __restrict__ ic2,
                                                   const u16* __restrict__ lwb,
                                                   float* __restrict__ sig) {
    int tid = threadIdx.x;
    int wid = blockIdx.x * 4 + (tid >> 6);
    int lane = tid & 63;
    int r = lane & 15;
    int quad = lane >> 4;
    int mt = wid & 3;
    int nt = wid >> 2;

    int n = nt * 16 + r;
    const u16* pA = lwb + (size_t)mt * 16 * 1024 + quad * 128 + r * 8;
    const u16* pB = ic2 + (size_t)n * 1024 + quad * 8;

    f32x4 acc = {0.f, 0.f, 0.f, 0.f};
#pragma unroll 4
    for (int kk = 0; kk < 32; ++kk) {
        bf16x8 a = *(const bf16x8*)pA;
        bf16x8 bv = *(const bf16x8*)pB;
        acc = __builtin_amdgcn_mfma_f32_16x16x32_bf16(a, bv, acc, 0, 0, 0);
        pA += 512;
        pB += 32;
    }

    int b = n / 23, j = n % 23;
#pragma unroll
    for (int jj = 0; jj < 4; ++jj) {
        int o = mt * 16 + quad * 4 + jj;
        float v = 1.f / (1.f + expf(-acc[jj]));
        sig[(size_t)b * 1472 + (size_t)o * 23 + j] = v;
    }
}

// ---------------- final interleave/shuffle ----------------
__global__ void shuffle_out_kernel(const float* __restrict__ sig, float* __restrict__ out) {
    int idx = blockIdx.x * blockDim.x + threadIdx.x;
    if (idx >= 64 * 768) return;
    int o = idx % 32;
    int j = (idx / 32) % 24;
    int b = idx / 768;
    const float* s = sig + (size_t)b * 64 * 23;
    float v;
    if (j == 0)       v = s[o * 23];
    else if (j == 23) v = s[(o + 32) * 23 + 22];
    else              v = 0.5f * (s[(o + 32) * 23 + (j - 1)] + s[o * 23 + j]);
    out[idx] = v;
}

extern "C" void kernel_launch(void* const* d_in, const int* in_sizes, int n_in,
                              void* d_out, int out_size, void* d_ws, size_t ws_size,
                              hipStream_t stream) {
    (void)in_sizes; (void)n_in; (void)out_size; (void)ws_size;

    const float* x = (const float*)d_in[0];
    const float* w[5]; const float* g[5]; const float* bb[5];
    for (int i = 0; i < 5; ++i) {
        w[i]  = (const float*)d_in[1 + 3 * i];
        g[i]  = (const float*)d_in[2 + 3 * i];
        bb[i] = (const float*)d_in[3 + 3 * i];
    }
    const float* w5 = (const float*)d_in[16];
    const float* lw = (const float*)d_in[17];
    float* out = (float*)d_out;

    // ---- workspace layout (~63 MB) ----
    float* ws    = (float*)d_ws;
    u16*   A     = (u16*)ws;                    // conv-out bf16
    u16*   P     = (u16*)(ws + 6291456);        // padded inputs
    u16*   wbf   = (u16*)(ws + 13115392);       // 697,344 u16
    float* ss    = ws + 13472256;               // 512 f32
    u16*   w5b   = (u16*)(ws + 13474304);       // 1,048,576 u16
    u16*   ic    = (u16*)(ws + 13998592);       // 1,507,328 u16
    u16*   ic2   = (u16*)(ws + 14752256);       // 1,507,328 u16
    u16*   lwb   = (u16*)(ws + 15505920);       // 65,536 u16
    float* partB = ws + 15538688;               // 98,304 f32
    float* sig   = ws + 4194304;                // (64,64,23) f32 (dead region at tail time)

    const size_t wofs[5] = {0, 1024, 9216, 41984, 173056};

    hipLaunchKernelGGL(prep, dim3(13478), dim3(256), 0, stream,
                       x, w[0], w[1], w[2], w[3], w[4], w5, lw, wbf, w5b, lwb, P);

    // L0: MT=1, NT=8 -> 1536 blocks, NSLOT=1536
    hipLaunchKernelGGL((conv_mfma<16, 4, 64, 64, 768, 66, 776, 1, 8>),
                       dim3(1536), dim3(256), 0, stream, P, wbf + wofs[0], A, partB);
    hipLaunchKernelGGL((bn_finalize_blk<16, 1536>), dim3(16), dim3(256), 0, stream,
                       partB, g[0], bb[0], ss, 1.f / 786432.f);
    hipLaunchKernelGGL((bn_pad_v<16, 32, 384>), dim3(6664), dim3(256), 0, stream, A, ss, P);

    // L1: MT=2, NT=2 -> 1536 blocks, NSLOT=1536
    hipLaunchKernelGGL((conv_mfma<32, 16, 256, 32, 384, 34, 392, 2, 2>),
                       dim3(1536), dim3(256), 0, stream, P, wbf + wofs[1], A, partB);
    hipLaunchKernelGGL((bn_finalize_blk<32, 1536>), dim3(32), dim3(256), 0, stream,
                       partB, g[1], bb[1], ss, 1.f / 196608.f);
    hipLaunchKernelGGL((bn_pad_v<32, 16, 192>), dim3(3600), dim3(256), 0, stream, A, ss, P);

    // L2: MT=4, NT=2 -> 384 blocks, NSLOT=384
    hipLaunchKernelGGL((conv_mfma<64, 32, 512, 16, 192, 18, 200, 4, 2>),
                       dim3(384), dim3(256), 0, stream, P, wbf + wofs[2], A, partB);
    hipLaunchKernelGGL((bn_finalize_blk<64, 384>), dim3(64), dim3(256), 0, stream,
                       partB, g[2], bb[2], ss, 1.f / 49152.f);
    hipLaunchKernelGGL((bn_pad_v<64, 8, 96>), dim3(2080), dim3(256), 0, stream, A, ss, P);

    // L3: MT=2 (MG=4), NT=1 -> 768 blocks, NSLOT=192
    hipLaunchKernelGGL((conv_mfma<128, 64, 1024, 8, 96, 10, 104, 2, 1>),
                       dim3(768), dim3(256), 0, stream, P, wbf + wofs[3], A, partB);
    hipLaunchKernelGGL((bn_finalize_blk<128, 192>), dim3(128), dim3(256), 0, stream,
                       partB, g[3], bb[3], ss, 1.f / 12288.f);
    hipLaunchKernelGGL((bn_pad_v<128, 4, 48>), dim3(1344), dim3(256), 0, stream, A, ss, P);

    // L4: MT=2 (MG=8), NT=1 -> 384 blocks, NSLOT=48
    hipLaunchKernelGGL((conv_mfma<256, 128, 2048, 4, 48, 6, 56, 2, 1>),
                       dim3(384), dim3(256), 0, stream, P, wbf + wofs[4], A, partB);
    hipLaunchKernelGGL((bn_finalize_blk<256, 48>), dim3(256), dim3(256), 0, stream,
                       partB, g[4], bb[4], ss, 1.f / 3072.f);
    hipLaunchKernelGGL(im2col5, dim3(5888), dim3(256), 0, stream, A, ss, ic);

    // tail
    hipLaunchKernelGGL(conv5_lds, dim3(368), dim3(256), 0, stream, ic, w5b, ic2);
    hipLaunchKernelGGL(linear_mfma, dim3(92), dim3(256), 0, stream, ic2, lwb, sig);
    hipLaunchKernelGGL(shuffle_out_kernel, dim3((64 * 768 + 255) / 256), dim3(256), 0, stream,
                       sig, out);
}